// Round 3
// 160.822 us; speedup vs baseline: 1.0073x; 1.0073x over previous
//
#include <hip/hip_runtime.h>
#include <hip/hip_bf16.h>
#include <cstdint>

typedef __attribute__((ext_vector_type(8))) short short8;
typedef __attribute__((ext_vector_type(16))) float f32x16;

#if __has_builtin(__builtin_amdgcn_exp2f)
#define EXP2F(x) __builtin_amdgcn_exp2f(x)
#else
#define EXP2F(x) exp2f(x)
#endif

#define MFMA32(A, B, C) __builtin_amdgcn_mfma_f32_32x32x16_bf16((A), (B), (C), 0, 0, 0)

// fp32 -> bf16, round-to-nearest-even (proven baseline path)
__device__ __forceinline__ unsigned short f2bf(float f) {
  unsigned int u = __builtin_bit_cast(unsigned int, f);
  u += 0x7FFFu + ((u >> 16) & 1u);
  return (unsigned short)(u >> 16);
}

// ---------------------------------------------------------------------------
// Prep: Wt[which][n][k] = f2bf(W_which[k][n]),  3 x 64 x 512 bf16.
// ---------------------------------------------------------------------------
__global__ __launch_bounds__(256) void prep_wt(
    const float* __restrict__ Wq, const float* __restrict__ Wk,
    const float* __restrict__ Wv, unsigned short* __restrict__ Wt)
{
  int idx = blockIdx.x * 256 + threadIdx.x;     // 384 blocks
  int which = idx >> 15;
  int rem = idx & 32767;
  int n = rem >> 9;
  int k = rem & 511;
  const float* W = (which == 0) ? Wq : (which == 1) ? Wk : Wv;
  Wt[idx] = f2bf(W[k * 64 + n]);
}

// ---------------------------------------------------------------------------
// Fused projection, LDS-staged GEMM, double-buffered:
//   per chunk: issue next chunk's 8 float4 global loads FIRST, MFMA on the
//   current LDS buffer, then pack+ds_write the prefetched data, 1 barrier.
//   Buffer safety: chunk c lives in Xs[c&1]; writes to Xs[(c+1)&1] at c are
//   separated from the last reads of that buffer (at c-1) by the c-1 barrier.
//   LDS 2x17KB = 34KB -> still 3 blocks/CU.
// ---------------------------------------------------------------------------
__global__ __launch_bounds__(256, 3) void proj_kernel(
    const float* __restrict__ qin, const float* __restrict__ kin,
    const float* __restrict__ vin, const unsigned short* __restrict__ Wt,
    const float* __restrict__ bq, const float* __restrict__ bk,
    const float* __restrict__ bv,
    unsigned short* __restrict__ Qo, unsigned short* __restrict__ Ko,
    unsigned short* __restrict__ Vto)
{
  __shared__ unsigned short Xs[2][64 * 136];   // 2 x 17.4 KB; Xs[0] reused as TB

  const int which = blockIdx.y;
  const float* X    = (which == 0) ? qin : (which == 1) ? kin : vin;
  const float* bias = (which == 0) ? bq  : (which == 1) ? bk  : bv;

  const int tid = threadIdx.x;
  const int lane = tid & 63, wv = tid >> 6;
  const int h = lane >> 5, l31 = lane & 31;
  const int grp = wv & 1, nh = wv >> 1;
  const int m0 = blockIdx.x * 64;

  const unsigned short* wcol =
      Wt + (size_t)which * 64 * 512 + (size_t)(nh * 32 + l31) * 512 + h * 8;

  const int srow = tid >> 5;        // 0..7
  const int skoff = tid & 31;       // 16B units within 512B chunk-row
  const float* xg = X + (size_t)(m0 + srow) * 512 + skoff * 4;

  // prologue: stage chunk 0 into buffer 0
  float4 ld[8];
  #pragma unroll
  for (int j = 0; j < 8; ++j)
    ld[j] = *(const float4*)(xg + (size_t)(8 * j) * 512);
  #pragma unroll
  for (int j = 0; j < 8; ++j) {
    unsigned int w0 = (unsigned int)f2bf(ld[j].x) | ((unsigned int)f2bf(ld[j].y) << 16);
    unsigned int w1 = (unsigned int)f2bf(ld[j].z) | ((unsigned int)f2bf(ld[j].w) << 16);
    uint2 pw; pw.x = w0; pw.y = w1;
    *(uint2*)(&Xs[0][(srow + 8 * j) * 136 + skoff * 4]) = pw;
  }
  __syncthreads();

  f32x16 acc = {};
  for (int c = 0; c < 4; ++c) {
    if (c < 3) {                                  // issue next chunk's loads early
      #pragma unroll
      for (int j = 0; j < 8; ++j)
        ld[j] = *(const float4*)(xg + (size_t)(8 * j) * 512 + (c + 1) * 128);
    }
    const unsigned short* arow = &Xs[c & 1][(grp * 32 + l31) * 136 + h * 8];
    const unsigned short* wk = wcol + c * 128;
    #pragma unroll
    for (int ks = 0; ks < 8; ++ks) {
      short8 af = *(const short8*)(arow + ks * 16);
      short8 bf = *(const short8*)(wk + ks * 16);
      acc = MFMA32(af, bf, acc);
    }
    if (c < 3) {                                  // write other buffer, 1 barrier
      #pragma unroll
      for (int j = 0; j < 8; ++j) {
        unsigned int w0 = (unsigned int)f2bf(ld[j].x) | ((unsigned int)f2bf(ld[j].y) << 16);
        unsigned int w1 = (unsigned int)f2bf(ld[j].z) | ((unsigned int)f2bf(ld[j].w) << 16);
        uint2 pw; pw.x = w0; pw.y = w1;
        *(uint2*)(&Xs[(c + 1) & 1][(srow + 8 * j) * 136 + skoff * 4]) = pw;
      }
      __syncthreads();
    }
  }

  const float bv0 = bias[nh * 32 + l31];

  if (which < 2) {
    const float scale = which ? 1.0f : 0.18033688f;  // (1/sqrt(64))*log2(e) for Q
    unsigned short* Y = which ? Ko : Qo;
    #pragma unroll
    for (int r = 0; r < 16; ++r) {
      int row = (r & 3) + 8 * (r >> 2) + 4 * h;      // C/D layout [m101]
      Y[(size_t)(m0 + grp * 32 + row) * 64 + nh * 32 + l31] =
          f2bf((acc[r] + bv0) * scale);
    }
  } else {
    __syncthreads();                // all waves done with Xs before TB overwrite
    unsigned short* TB = &Xs[0][0]; // [64 n][68 s]
    #pragma unroll
    for (int r = 0; r < 16; ++r) {
      int row = (r & 3) + 8 * (r >> 2) + 4 * h;
      TB[(nh * 32 + l31) * 68 + grp * 32 + row] = f2bf(acc[r] + bv0);
    }
    __syncthreads();
    int bidx = blockIdx.x >> 5;        // 32 blocks per batch (64 rows each)
    int s0 = (blockIdx.x & 31) * 64;
    for (int i = tid; i < 64 * 16; i += 256) {   // 64 n x 16 ushort4 chunks
      int n = i >> 4, cs = i & 15;
      ushort4 v4 = *(const ushort4*)(TB + n * 68 + cs * 4);
      *(ushort4*)(Vto + ((size_t)bidx * 64 + n) * 2048 + s0 + cs * 4) = v4;
    }
  }
}

// ---------------------------------------------------------------------------
// Flash attention, transposed formulation. Round 3 = safe bisect:
//  - REVERTED to baseline-proven __shfl_xor exchange + f2bf packing
//    (permlane/cvt_pk inline asm removed entirely)
//  - KEPT: tree reductions (depth 15 -> 5), defer-max (THR=8, log2 domain),
//    K/V register prefetch, s_setprio around MFMA clusters
// ---------------------------------------------------------------------------
__global__ __launch_bounds__(512, 2) void attn_kernel(
    const unsigned short* __restrict__ Q, const unsigned short* __restrict__ K,
    const unsigned short* __restrict__ Vt, float* __restrict__ out)
{
  __shared__ float ObS[4][16][64];
  __shared__ float MpS[4][64];
  __shared__ float LpS[4][64];

  const int tid = threadIdx.x;
  const int lane = tid & 63, w = tid >> 6;
  const int h = lane >> 5, l31 = lane & 31;
  const int b = blockIdx.y;
  const int q0 = blockIdx.x * 64;

  short8 qf[2][4];
  #pragma unroll
  for (int qt = 0; qt < 2; ++qt) {
    const unsigned short* qp = Q + ((size_t)(b * 2048 + q0 + qt * 32 + l31)) * 64 + h * 8;
    #pragma unroll
    for (int c = 0; c < 4; ++c) qf[qt][c] = *(const short8*)(qp + c * 16);
  }

  f32x16 o00 = {}, o01 = {}, o10 = {}, o11 = {};
  float m0 = -1e30f, m1 = -1e30f, ls0 = 0.f, ls1 = 0.f;

  const unsigned short* Kp  = K  + ((size_t)(b * 2048 + w * 256 + l31)) * 64 + h * 8;
  const unsigned short* Vp0 = Vt + ((size_t)(b * 64 + l31)) * 2048 + w * 256 + h * 8;
  const unsigned short* Vp1 = Vp0 + (size_t)32 * 2048;

  short8 kf[4], vf0[2], vf1[2];
  #pragma unroll
  for (int c = 0; c < 4; ++c) kf[c] = *(const short8*)(Kp + c * 16);
  vf0[0] = *(const short8*)(Vp0); vf0[1] = *(const short8*)(Vp0 + 16);
  vf1[0] = *(const short8*)(Vp1); vf1[1] = *(const short8*)(Vp1 + 16);

  // softmax + PV for one 32-query tile; sT is S^T[key r][q l31]
  auto process = [&](f32x16 sT, float &m, float &ls, f32x16 &oA, f32x16 &oB) {
    // tree max over 16 regs, then cross-half via proven shfl
    float tm[8];
    #pragma unroll
    for (int i = 0; i < 8; ++i) tm[i] = fmaxf(sT[2 * i], sT[2 * i + 1]);
    #pragma unroll
    for (int i = 0; i < 4; ++i) tm[i] = fmaxf(tm[i], tm[i + 4]);
    float mx = fmaxf(fmaxf(tm[0], tm[1]), fmaxf(tm[2], tm[3]));
    mx = fmaxf(mx, __shfl_xor(mx, 32, 64));
    // defer-max: rescale only when tile max exceeds running max by >8
    // (log2 domain -> P bounded by 2^8; fp32 accum has ample headroom)
    if (__any(mx > m + 8.0f)) {
      float mnew = fmaxf(m, mx);
      float alpha = EXP2F(m - mnew);
      m = mnew;
      ls *= alpha; oA *= alpha; oB *= alpha;
    }
    float p[16];
    #pragma unroll
    for (int r = 0; r < 16; ++r) p[r] = EXP2F(sT[r] - m);
    // tree sum + cross-half via proven shfl
    float ts[8];
    #pragma unroll
    for (int i = 0; i < 8; ++i) ts[i] = p[2 * i] + p[2 * i + 1];
    #pragma unroll
    for (int i = 0; i < 4; ++i) ts[i] += ts[i + 4];
    float rs = (ts[0] + ts[1]) + (ts[2] + ts[3]);
    rs += __shfl_xor(rs, 32, 64);
    ls += rs;
    // baseline-proven P pack + cross-half exchange
    unsigned int pk[8];
    #pragma unroll
    for (int i = 0; i < 8; ++i)
      pk[i] = (unsigned int)f2bf(p[2 * i]) | ((unsigned int)f2bf(p[2 * i + 1]) << 16);
    unsigned int ex[8];
    #pragma unroll
    for (int i = 0; i < 8; ++i) ex[i] = (unsigned int)__shfl_xor((int)pk[i], 32, 64);
    uint4 cc0, cc1;
    if (h == 0) { cc0 = make_uint4(pk[0], pk[1], ex[0], ex[1]); cc1 = make_uint4(pk[4], pk[5], ex[4], ex[5]); }
    else        { cc0 = make_uint4(ex[2], ex[3], pk[2], pk[3]); cc1 = make_uint4(ex[6], ex[7], pk[6], pk[7]); }
    short8 P0 = __builtin_bit_cast(short8, cc0);
    short8 P1 = __builtin_bit_cast(short8, cc1);
    __builtin_amdgcn_s_setprio(1);
    oA = MFMA32(vf0[0], P0, oA); oA = MFMA32(vf0[1], P1, oA);
    oB = MFMA32(vf1[0], P0, oB); oB = MFMA32(vf1[1], P1, oB);
    __builtin_amdgcn_s_setprio(0);
  };

  for (int st = 0; st < 8; ++st) {
    f32x16 s0 = {}, s1 = {};
    __builtin_amdgcn_s_setprio(1);
    #pragma unroll
    for (int c = 0; c < 4; ++c) s0 = MFMA32(kf[c], qf[0][c], s0);
    #pragma unroll
    for (int c = 0; c < 4; ++c) s1 = MFMA32(kf[c], qf[1][c], s1);
    __builtin_amdgcn_s_setprio(0);
    if (st < 7) {                    // kf dead: reload now, lands during softmax+PV
      #pragma unroll
      for (int c = 0; c < 4; ++c)
        kf[c] = *(const short8*)(Kp + (size_t)(st + 1) * 2048 + c * 16);
    }
    process(s0, m0, ls0, o00, o10);
    process(s1, m1, ls1, o01, o11);
    if (st < 7) {                    // vf dead: reload, lands during next QK+softmax
      vf0[0] = *(const short8*)(Vp0 + (st + 1) * 32);
      vf0[1] = *(const short8*)(Vp0 + (st + 1) * 32 + 16);
      vf1[0] = *(const short8*)(Vp1 + (st + 1) * 32);
      vf1[1] = *(const short8*)(Vp1 + (st + 1) * 32 + 16);
    }
  }

  for (int half = 4; half > 0; half >>= 1) {
    const bool writer = (w >= half) && (w < 2 * half);
    const bool merger = (w < half);
    __syncthreads();
    if (writer && h == 0) {
      MpS[w - half][l31] = m0;      LpS[w - half][l31] = ls0;
      MpS[w - half][32 + l31] = m1; LpS[w - half][32 + l31] = ls1;
    }
    __syncthreads();
    float fb0 = 0.f, fb1 = 0.f;
    if (merger) {
      float pm0 = MpS[w][l31],      pl0 = LpS[w][l31];
      float pm1 = MpS[w][32 + l31], pl1 = LpS[w][32 + l31];
      float nm0 = fmaxf(m0, pm0), nm1 = fmaxf(m1, pm1);
      float fa0 = EXP2F(m0 - nm0); fb0 = EXP2F(pm0 - nm0);
      float fa1 = EXP2F(m1 - nm1); fb1 = EXP2F(pm1 - nm1);
      m0 = nm0; m1 = nm1;
      ls0 = ls0 * fa0 + pl0 * fb0; ls1 = ls1 * fa1 + pl1 * fb1;
      o00 *= fa0; o10 *= fa0; o01 *= fa1; o11 *= fa1;
    }
    __syncthreads();
    if (writer) {
      #pragma unroll
      for (int r = 0; r < 16; ++r) ObS[w - half][r][lane] = o00[r]; }
    __syncthreads();
    if (merger) {
      #pragma unroll
      for (int r = 0; r < 16; ++r) o00[r] += ObS[w][r][lane] * fb0; }
    __syncthreads();
    if (writer) {
      #pragma unroll
      for (int r = 0; r < 16; ++r) ObS[w - half][r][lane] = o01[r]; }
    __syncthreads();
    if (merger) {
      #pragma unroll
      for (int r = 0; r < 16; ++r) o01[r] += ObS[w][r][lane] * fb1; }
    __syncthreads();
    if (writer) {
      #pragma unroll
      for (int r = 0; r < 16; ++r) ObS[w - half][r][lane] = o10[r]; }
    __syncthreads();
    if (merger) {
      #pragma unroll
      for (int r = 0; r < 16; ++r) o10[r] += ObS[w][r][lane] * fb0; }
    __syncthreads();
    if (writer) {
      #pragma unroll
      for (int r = 0; r < 16; ++r) ObS[w - half][r][lane] = o11[r]; }
    __syncthreads();
    if (merger) {
      #pragma unroll
      for (int r = 0; r < 16; ++r) o11[r] += ObS[w][r][lane] * fb1; }
  }

  if (w == 0) {
    float i0 = 1.0f / ls0, i1 = 1.0f / ls1;
    o00 *= i0; o10 *= i0; o01 *= i1; o11 *= i1;
    #pragma unroll
    for (int qt = 0; qt < 2; ++qt) {
      int q = qt * 32 + l31;
      float* ob = out + ((size_t)(b * 2048 + q0 + q)) * 64 + 4 * h;
      const f32x16 a = qt ? o01 : o00;
      const f32x16 c = qt ? o11 : o10;
      #pragma unroll
      for (int g = 0; g < 4; ++g) {
        *(float4*)(ob + 8 * g)      = make_float4(a[4*g], a[4*g+1], a[4*g+2], a[4*g+3]);
        *(float4*)(ob + 32 + 8 * g) = make_float4(c[4*g], c[4*g+1], c[4*g+2], c[4*g+3]);
      }
    }
  }
}

extern "C" void kernel_launch(void* const* d_in, const int* in_sizes, int n_in,
                              void* d_out, int out_size, void* d_ws, size_t ws_size,
                              hipStream_t stream) {
  const float* qin = (const float*)d_in[0];
  const float* kin = (const float*)d_in[1];
  const float* vin = (const float*)d_in[2];
  const float* Wq  = (const float*)d_in[3];
  const float* bq  = (const float*)d_in[4];
  const float* Wk  = (const float*)d_in[5];
  const float* bk  = (const float*)d_in[6];
  const float* Wv  = (const float*)d_in[7];
  const float* bv  = (const float*)d_in[8];

  unsigned short* Qo  = (unsigned short*)d_ws;            // [8*2048][64] bf16 (pre-scaled)
  unsigned short* Ko  = Qo + (size_t)16384 * 64;          // [8*2048][64] bf16
  unsigned short* Vto = Ko + (size_t)16384 * 64;          // [8][64][2048] bf16 (transposed)
  unsigned short* Wt  = Vto + (size_t)8 * 64 * 2048;      // [3][64][512] bf16 W^T
  float* out = (float*)d_out;

  hipLaunchKernelGGL(prep_wt, dim3(384), dim3(256), 0, stream, Wq, Wk, Wv, Wt);
  hipLaunchKernelGGL(proj_kernel, dim3(256, 3), dim3(256), 0, stream,
                     qin, kin, vin, Wt, bq, bk, bv, Qo, Ko, Vto);
  hipLaunchKernelGGL(attn_kernel, dim3(32, 8), dim3(512), 0, stream, Qo, Ko, Vto, out);
}